// Round 14
// baseline (204.831 us; speedup 1.0000x reference)
//
#include <hip/hip_runtime.h>
#include <hip/hip_bf16.h>
#include <math.h>

#define SEQ_LEN 128
#define BATCH   32
#define T       32
#define TT      (T*T)     // 1024
#define TTT     (T*T*T)   // 32768
#define START   30
#define END     31

#define LOG2E   1.44269504088896f
#define OFF4    5.77078016355587f   // 4 * log2(e)

typedef unsigned long long u64;

__device__ __forceinline__ u64 pt_pack(int tag, float v) {
    union { float f; unsigned int u; } c; c.f = v;
    return ((u64)(unsigned int)tag << 32) | (u64)c.u;
}
__device__ __forceinline__ float pt_val(u64 w) {
    union { unsigned int u; float f; } c; c.u = (unsigned int)w; return c.f;
}
__device__ __forceinline__ int pt_tag(u64 w) { return (int)(w >> 32); }

__device__ __forceinline__ u64 ald64(const u64* p) {
    return __hip_atomic_load(p, __ATOMIC_RELAXED, __HIP_MEMORY_SCOPE_AGENT);
}
__device__ __forceinline__ void ast64(u64* p, u64 v) {
    __hip_atomic_store(p, v, __ATOMIC_RELAXED, __HIP_MEMORY_SCOPE_AGENT);
}

// fast-path primitives: plain store lands in the local (write-through L1 ->)
// XCD L2; sc0 load bypasses L1 and reads that L2. Tags make any staleness
// harmless (stale line = stale tag = rejected).
__device__ __forceinline__ void st_plain(u64* p, u64 v) {
    asm volatile("global_store_dwordx2 %0, %1, off" :: "v"(p), "v"(v) : "memory");
}
__device__ __forceinline__ void ld_fast2(const u64* p0, const u64* p1,
                                         u64& r0, u64& r1) {
    asm volatile("global_load_dwordx2 %0, %2, off sc0\n\t"
                 "global_load_dwordx2 %1, %3, off sc0\n\t"
                 "s_waitcnt vmcnt(0)"
                 : "=&v"(r0), "=&v"(r1) : "v"(p0), "v"(p1) : "memory");
}

// raw barrier: drain LDS ops only; global prefetch/publish stay in flight
#define BLOCK_SYNC() do {                                   \
    asm volatile("s_waitcnt lgkmcnt(0)" ::: "memory");      \
    __builtin_amdgcn_sched_barrier(0);                      \
    __builtin_amdgcn_s_barrier();                           \
    __builtin_amdgcn_sched_barrier(0);                      \
} while (0)

// ---------------------------------------------------------------------------
// Kernel 1: tg_energy gather. ws[0..15] <- per-block partial sums.
// ---------------------------------------------------------------------------
__global__ __launch_bounds__(256) void tg_kernel(const float* __restrict__ scores,
                                                 const int*   __restrict__ target,
                                                 const int*   __restrict__ mask,
                                                 float*       __restrict__ ws) {
    int idx = blockIdx.x * 256 + threadIdx.x;
    float v = 0.0f;
    if (mask[idx] != 0) v = scores[(size_t)idx * TTT + target[idx]];
    #pragma unroll
    for (int off = 32; off > 0; off >>= 1) v += __shfl_down(v, off, 64);
    __shared__ float partial[4];
    int wave = threadIdx.x >> 6, lane = threadIdx.x & 63;
    if (lane == 0) partial[wave] = v;
    __syncthreads();
    if (threadIdx.x == 0)
        ws[blockIdx.x] = partial[0] + partial[1] + partial[2] + partial[3];
}

// ---------------------------------------------------------------------------
// Kernel 2: init tagged buffers, slow AND fast copies (full overwrite each
// launch: replay-safe). ptF[b]: parity1 <- Q_1 (tag 1) at word j*32+i,
// parity0 <- 0. ptB[b]: parity0 <- R_127 (tag 128, indicator), parity1 <- 0.
// ---------------------------------------------------------------------------
__global__ __launch_bounds__(256) void init_dfb(const float* __restrict__ scores,
                                                u64* __restrict__ ptF,
                                                u64* __restrict__ ptB,
                                                u64* __restrict__ ftF,
                                                u64* __restrict__ ftB) {
    const int blk = blockIdx.x, tid = threadIdx.x;
    if (blk < BATCH) {
        const int b = blk;
        u64* pt = ptF + (size_t)b * 2048;
        u64* ft = ftF + (size_t)b * 2048;
        #pragma unroll
        for (int q = 0; q < 4; ++q) {
            int e = q * 256 + tid;           // e = j*32 + i
            int i = e & 31, j = e >> 5;
            float p1 = scores[(size_t)(0*BATCH + b)*TTT + START*TT + START*T + i];
            float s1 = scores[(size_t)(1*BATCH + b)*TTT + START*TT + i*T + j];
            u64 w = pt_pack(1, __expf(p1 + s1));
            pt[1024 + e] = w;  ft[1024 + e] = w;
            pt[e]        = 0ULL;  ft[e] = 0ULL;
        }
    } else {
        const int b = blk - BATCH;
        u64* pt = ptB + (size_t)b * 2048;
        u64* ft = ftB + (size_t)b * 2048;
        #pragma unroll
        for (int q = 0; q < 4; ++q) {
            int e = q * 256 + tid;           // e = i*32 + j
            float v = (e == END*T + END) ? 1.0f : 0.0f;
            u64 w = pt_pack(128, v);
            pt[e] = w;  ft[e] = w;
            pt[1024 + e] = 0ULL;  ft[1024 + e] = 0ULL;
        }
    }
}

// ---------------------------------------------------------------------------
// Kernel 3: distributed fwd/bwd scan with same-XCD L2 fast exchange.
// 512 blocks x 512 threads, 2 blocks/CU. chain = bid&63 (b=chain&31,
// dirB=chain>=32), g = bid>>6 -> chain blocks are bids == chain (mod 8):
// same XCD under round-robin dispatch (HEURISTIC ONLY -- correctness never
// depends on it; slow MALL path is probed every spin iteration).
// Protocol otherwise identical to r11 (proven, absmax 0): per-word tagged
// u64, wave0 polls its contiguous 128-word range EVERY step, 2 parity
// buffers, B1 gates all lanes, owner lanes publish directly.
// ---------------------------------------------------------------------------
__global__ __launch_bounds__(512, 4) void scan_xl2(const float* __restrict__ scores,
                                                   const int*   __restrict__ maskI,
                                                   u64*         __restrict__ ptF,
                                                   u64*         __restrict__ ptB,
                                                   u64*         __restrict__ ftF,
                                                   u64*         __restrict__ ftB) {
    const int bid   = blockIdx.x;
    const int chain = bid & 63;
    const int g     = bid >> 6;
    const int b     = chain & 31;
    const bool dirB = (chain >> 5) != 0;
    const int tid   = threadIdx.x;
    const int lane  = tid & 63;

    // mask as wave-uniform bitfields (no LDS traffic in the loop)
    const u64 mlo = __ballot(maskI[lane * BATCH + b] != 0);
    const u64 mhi = __ballot(maskI[(64 + lane) * BATCH + b] != 0);
    auto act_of = [&](int t) {
        return (((t < 64) ? (mlo >> t) : (mhi >> (t - 64))) & 1ULL) != 0ULL;
    };

    u64* const pt = (dirB ? ptB : ptF) + (size_t)b * 2048;
    u64* const ft = (dirB ? ftB : ftF) + (size_t)b * 2048;
    const int i0 = tid >> 5;                 // 0..15
    const int f  = tid & 31;
    const size_t offA = (size_t)i0 * TT + g * 128 + f * 4;
    auto sb = [&](int t) { return scores + ((size_t)t * BATCH + b) * TTT; };

    // dual-path poll: fast (sc0, local L2) each iteration, slow (MALL) on miss
    auto poll128 = [&](int spar, int tagw, u64& w0, u64& w1) {
        const u64* src  = pt + (size_t)spar * 1024 + 128 * g;
        const u64* fsrc = ft + (size_t)spar * 1024 + 128 * g;
        bool d0 = false, d1 = false;
        for (;;) {
            u64 f0, f1;
            ld_fast2(fsrc + lane, fsrc + 64 + lane, f0, f1);
            if (!d0 && pt_tag(f0) == tagw) { w0 = f0; d0 = true; }
            if (!d1 && pt_tag(f1) == tagw) { w1 = f1; d1 = true; }
            if (__all(d0 && d1)) break;
            if (!d0) { u64 x = ald64(src + lane);      if (pt_tag(x) == tagw) { w0 = x; d0 = true; } }
            if (!d1) { u64 x = ald64(src + 64 + lane); if (pt_tag(x) == tagw) { w1 = x; d1 = true; } }
            if (__all(d0 && d1)) break;
        }
    };

    if (!dirB) {
        // ------------------------------ FORWARD ------------------------------
        __shared__ __align__(16) float sm[4][128 * 33];   // tile t -> buf t&3
        __shared__ __align__(16) float pld[2][128];
        const int oF = tid >> 2, s4 = tid & 3;            // output oF=(jj,k)
        const int jj = oF >> 5, k = oF & 31;
        const int jcol = 4 * g + jj;
        const int ownW = k * 32 + jcol;                   // owned state word
        float lastval = pt_val(pt[1024 + ownW]);          // init parity1 value

        float4 X0, X1;
        auto issue = [&](int t) {
            const float* p = sb(t) + offA;
            X0 = *(const float4*)p; X1 = *(const float4*)(p + 16 * TT);
        };
        auto scat = [&](int bf) {
            #pragma unroll
            for (int q = 0; q < 4; ++q) {
                sm[bf][(f*4 + q)*33 + i0]      = (&X0.x)[q];
                sm[bf][(f*4 + q)*33 + i0 + 16] = (&X1.x)[q];
            }
        };

        issue(2); scat(2);
        issue(3); scat(3);
        issue(4);
        __syncthreads();

        for (int t = 2; t <= 64; ++t) {
            const bool act  = act_of(t);
            const int  pbuf = t & 1;
            if (t + 2 <= 64) scat((t + 2) & 3);
            if (t + 3 <= 64) issue(t + 3);
            if (tid < 64) {
                u64 w0, w1;
                poll128((t - 1) & 1, t - 1, w0, w1);
                pld[pbuf][lane]      = pt_val(w0);
                pld[pbuf][lane + 64] = pt_val(w1);
            }
            BLOCK_SYNC();   // B1: pld + tile buf(t&3) ready; certifies reads
            u64* dst  = pt + (size_t)(t & 1) * 1024;
            u64* fdst = ft + (size_t)(t & 1) * 1024;
            if (act) {
                const float* row = &sm[t & 3][oF * 33 + 8 * s4];
                const float* pp  = &pld[pbuf][jj * 32 + 8 * s4];
                float acc = 0.f;
                #pragma unroll
                for (int m = 0; m < 8; ++m)
                    acc = fmaf(exp2f(fmaf(row[m], LOG2E, -OFF4)), pp[m], acc);
                acc += __shfl_xor(acc, 1, 64);
                acc += __shfl_xor(acc, 2, 64);
                if (s4 == 0) {
                    lastval = acc;
                    u64 w = pt_pack(t, acc);
                    st_plain(fdst + ownW, w);
                    ast64(dst + ownW, w);
                }
            } else {
                if (s4 == 0) {
                    u64 w = pt_pack(t, lastval);
                    st_plain(fdst + ownW, w);
                    ast64(dst + ownW, w);
                }
            }
        }
    } else {
        // ------------------------------ BACKWARD ------------------------------
        __shared__ __align__(16) float pld[2][128];
        const int jj = f >> 3, k4 = f & 7;
        const int jb = 4 * g + jj;
        const int ownW0 = i0 * 32 + jb, ownW1 = (i0 + 16) * 32 + jb;
        float last0 = pt_val(pt[ownW0]);      // init parity0 values
        float last1 = pt_val(pt[ownW1]);

        float4 A0, A1, B0, B1;
        auto issueR = [&](float4& Y0, float4& Y1, int t) {
            const float* p = sb(t) + offA;
            Y0 = *(const float4*)p; Y1 = *(const float4*)(p + 16 * TT);
        };

        auto stepB = [&](int t, const float4& X0, const float4& X1) {
            const bool act  = act_of(t);
            const int  pbuf = t & 1;
            if (tid < 64) {
                u64 w0, w1;
                poll128((t + 1) & 1, t + 1, w0, w1);
                pld[pbuf][lane]      = pt_val(w0);
                pld[pbuf][lane + 64] = pt_val(w1);
            }
            BLOCK_SYNC();
            u64* dst  = pt + (size_t)(t & 1) * 1024;
            u64* fdst = ft + (size_t)(t & 1) * 1024;
            if (act) {
                const float4 Rv = *(const float4*)&pld[pbuf][jj * 32 + 4 * k4];
                float a0, a1;
                a0 = exp2f(fmaf(X0.x, LOG2E, -OFF4)) * Rv.x;
                a0 = fmaf(exp2f(fmaf(X0.y, LOG2E, -OFF4)), Rv.y, a0);
                a0 = fmaf(exp2f(fmaf(X0.z, LOG2E, -OFF4)), Rv.z, a0);
                a0 = fmaf(exp2f(fmaf(X0.w, LOG2E, -OFF4)), Rv.w, a0);
                a1 = exp2f(fmaf(X1.x, LOG2E, -OFF4)) * Rv.x;
                a1 = fmaf(exp2f(fmaf(X1.y, LOG2E, -OFF4)), Rv.y, a1);
                a1 = fmaf(exp2f(fmaf(X1.z, LOG2E, -OFF4)), Rv.z, a1);
                a1 = fmaf(exp2f(fmaf(X1.w, LOG2E, -OFF4)), Rv.w, a1);
                a0 += __shfl_xor(a0, 1, 64); a0 += __shfl_xor(a0, 2, 64); a0 += __shfl_xor(a0, 4, 64);
                a1 += __shfl_xor(a1, 1, 64); a1 += __shfl_xor(a1, 2, 64); a1 += __shfl_xor(a1, 4, 64);
                if (k4 == 0) {
                    last0 = a0; last1 = a1;
                    u64 wA = pt_pack(t, a0), wB = pt_pack(t, a1);
                    st_plain(fdst + ownW0, wA);  ast64(dst + ownW0, wA);
                    st_plain(fdst + ownW1, wB);  ast64(dst + ownW1, wB);
                }
            } else {
                if (k4 == 0) {
                    u64 wA = pt_pack(t, last0), wB = pt_pack(t, last1);
                    st_plain(fdst + ownW0, wA);  ast64(dst + ownW0, wA);
                    st_plain(fdst + ownW1, wB);  ast64(dst + ownW1, wB);
                }
            }
        };

        issueR(A0, A1, 127);
        for (int t = 127; t >= 65; t -= 2) {
            if (t - 1 >= 65) issueR(B0, B1, t - 1);
            stepB(t, A0, A1);
            if (t - 2 >= 65) issueR(A0, A1, t - 2);
            if (t - 1 >= 65) stepB(t - 1, B0, B1);
        }
    }
}

// ---------------------------------------------------------------------------
// Kernel 4: finalize. Q_64 = ptF parity0 (tag 64); R_64 = ptB parity1 (tag 65).
// z_b = 4*cnt_b + log( sum Q_64 o R_64 ).
// ---------------------------------------------------------------------------
__global__ __launch_bounds__(1024) void finalize_dfb(const float* __restrict__ ws,
                                                     const u64*  __restrict__ ptF,
                                                     const u64*  __restrict__ ptB,
                                                     const int*  __restrict__ mask,
                                                     float*      __restrict__ out) {
    __shared__ float zs[32];
    const int w = threadIdx.x >> 6, lane = threadIdx.x & 63;
    for (int rep = 0; rep < 2; ++rep) {
        const int b = w + rep * 16;
        const u64* qf = ptF + (size_t)b * 2048;          // parity0
        const u64* rb = ptB + (size_t)b * 2048 + 1024;   // parity1
        float dot = 0.f;
        #pragma unroll
        for (int e = 0; e < 16; ++e) {
            const int x = lane + 64 * e;                 // x = k*32 + j
            dot += pt_val(qf[x]) * pt_val(rb[(x & 31) * 32 + (x >> 5)]);
        }
        float cnt = 0.f;
        {
            int t = 2 + lane;
            if (t < SEQ_LEN) cnt += (mask[t*BATCH + b] != 0) ? 1.f : 0.f;
            t += 64;
            if (t < SEQ_LEN) cnt += (mask[t*BATCH + b] != 0) ? 1.f : 0.f;
        }
        #pragma unroll
        for (int off = 32; off > 0; off >>= 1) {
            dot += __shfl_xor(dot, off, 64);
            cnt += __shfl_xor(cnt, off, 64);
        }
        if (lane == 0) zs[b] = 4.0f * cnt + logf(dot);
    }
    __syncthreads();
    if (threadIdx.x == 0) {
        float tg = 0.f, z = 0.f;
        #pragma unroll
        for (int i = 0; i < 16; ++i) tg += ws[i];
        #pragma unroll
        for (int i = 0; i < 32; ++i) z += zs[i];
        out[0] = (z - tg) / (float)BATCH;
    }
}

// ---------------------------------------------------------------------------
// Fallback (small ws): round-5 single-block-per-batch scan.
// ---------------------------------------------------------------------------
__global__ __launch_bounds__(1024) void scan_fast(const float* __restrict__ scores,
                                                  const int*   __restrict__ maskI,
                                                  float*       __restrict__ ws) {
    const int b    = blockIdx.x;
    const int tid  = threadIdx.x;
    const int w    = tid >> 6;
    const int lane = tid & 63;
    const int h    = lane >> 4;
    const int jp   = (lane >> 3) & 1;
    const int k4   = lane & 7;
    const int j    = w * 2 + jp;

    __shared__ float Q[2][TT];
    __shared__ int   lmask[SEQ_LEN];
    if (tid < SEQ_LEN) lmask[tid] = maskI[tid * BATCH + b];
    {
        int x = tid >> 5, y = tid & 31;
        float p1 = scores[(size_t)(0*BATCH + b)*TTT + START*TT + START*T + x];
        float s1 = scores[(size_t)(1*BATCH + b)*TTT + START*TT + x*T + y];
        Q[1][x*T + y] = __expf(p1 + s1);
    }
    __syncthreads();
    const int loff = h*8*TT + j*T + k4*4;
    float4 SA[8], SB[8];
    auto issue = [&](float4 (&S)[8], int t) {
        const float* p = scores + ((size_t)t*BATCH + b)*TTT + loff;
        #pragma unroll
        for (int m = 0; m < 8; ++m) S[m] = *(const float4*)(p + m*TT);
    };
    auto process = [&](float4 (&S)[8], int t) {
        const float* qc = Q[(t-1) & 1];
        float*       qn = Q[t & 1];
        #pragma unroll
        for (int m = 0; m < 8; ++m) {
            S[m].x = exp2f(fmaf(S[m].x, LOG2E, -OFF4));
            S[m].y = exp2f(fmaf(S[m].y, LOG2E, -OFF4));
            S[m].z = exp2f(fmaf(S[m].z, LOG2E, -OFF4));
            S[m].w = exp2f(fmaf(S[m].w, LOG2E, -OFF4));
        }
        float4 acc = make_float4(0.f, 0.f, 0.f, 0.f);
        #pragma unroll
        for (int m = 0; m < 8; ++m) {
            float q = qc[(h*8 + m)*T + j];
            acc.x = fmaf(S[m].x, q, acc.x);
            acc.y = fmaf(S[m].y, q, acc.y);
            acc.z = fmaf(S[m].z, q, acc.z);
            acc.w = fmaf(S[m].w, q, acc.w);
        }
        acc.x += __shfl_xor(acc.x, 16, 64); acc.y += __shfl_xor(acc.y, 16, 64);
        acc.z += __shfl_xor(acc.z, 16, 64); acc.w += __shfl_xor(acc.w, 16, 64);
        acc.x += __shfl_xor(acc.x, 32, 64); acc.y += __shfl_xor(acc.y, 32, 64);
        acc.z += __shfl_xor(acc.z, 32, 64); acc.w += __shfl_xor(acc.w, 32, 64);
        if (lane < 16) {
            if (lmask[t] != 0) *(float4*)&qn[j*T + k4*4] = acc;
            else               *(float4*)&qn[j*T + k4*4] = *(const float4*)&qc[j*T + k4*4];
        }
        asm volatile("s_waitcnt lgkmcnt(0)" ::: "memory");
        __builtin_amdgcn_s_barrier();
    };
    issue(SA, 2);
    for (int t = 2; t < SEQ_LEN; t += 2) {
        issue(SB, t + 1);
        process(SA, t);
        if (t + 2 < SEQ_LEN) issue(SA, t + 2);
        process(SB, t + 1);
    }
    if (tid == 0) {
        int cnt = 0;
        for (int t = 2; t < SEQ_LEN; ++t) cnt += (lmask[t] != 0);
        ws[16 + b] = 4.0f * (float)cnt + logf(Q[1][END*T + END]);
    }
}

__global__ void finalize_simple(const float* __restrict__ ws, float* __restrict__ out) {
    if (threadIdx.x == 0) {
        float tg = 0.f, z = 0.f;
        #pragma unroll
        for (int i = 0; i < 16; ++i) tg += ws[i];
        #pragma unroll
        for (int i = 0; i < 32; ++i) z += ws[16 + i];
        out[0] = (z - tg) / (float)BATCH;
    }
}

extern "C" void kernel_launch(void* const* d_in, const int* in_sizes, int n_in,
                              void* d_out, int out_size, void* d_ws, size_t ws_size,
                              hipStream_t stream) {
    const float* scores = (const float*)d_in[0];
    const int*   target = (const int*)d_in[1];
    const int*   mask   = (const int*)d_in[2];
    float* out = (float*)d_out;
    float* ws  = (float*)d_ws;
    u64*   ptF = (u64*)((char*)d_ws + 1024);
    u64*   ptB = ptF + (size_t)BATCH * 2048;
    u64*   ftF = ptB + (size_t)BATCH * 2048;
    u64*   ftB = ftF + (size_t)BATCH * 2048;
    const size_t need = 1024 + (size_t)4 * BATCH * 2048 * sizeof(u64);   // ~2.1 MB

    tg_kernel<<<16, 256, 0, stream>>>(scores, target, mask, ws);
    if (ws_size >= need) {
        init_dfb<<<2*BATCH, 256, 0, stream>>>(scores, ptF, ptB, ftF, ftB);
        scan_xl2<<<512, 512, 0, stream>>>(scores, mask, ptF, ptB, ftF, ftB);
        finalize_dfb<<<1, 1024, 0, stream>>>(ws, ptF, ptB, mask, out);
    } else {
        scan_fast<<<BATCH, 1024, 0, stream>>>(scores, mask, ws);
        finalize_simple<<<1, 64, 0, stream>>>(ws, out);
    }
}